// Round 5
// baseline (65.666 us; speedup 1.0000x reference)
//
#include <hip/hip_runtime.h>
#include <math.h>

#define BB   4
#define NN   4096
#define DD   128
#define NCLS 5
#define SS   800      // (N - NQ) / NCLS
#define KK   400      // int(0.5 * S)
#define NQ   96
#define MM   (NCLS*KK + NQ)   // 2096
#define NSUP (NCLS*SS)        // 4000

typedef float f4 __attribute__((ext_vector_type(4)));   // native vec for nontemporal builtins

// ---------------- fused score + top-400 per (b,class) ----------------
// Score numerics (verified R2, bit-exact vs np): z32 = round32(f64 dot);
// u=(z32+b)/100 f32; e=round32(exp(-u)); s=1/(1+e) f32.
// Ranking: descending (f32 score bits, inverted-index) packed keys -> ascending
// index on ties, matching np/jax stable top_k. Sort mechanism: register bitonic,
// shfl_xor for j<64, double-buffered LDS for j>=64 (verified R3).
__global__ void __launch_bounds__(1024)
topk_kernel(const float* __restrict__ X, const float* __restrict__ W,
            const float* __restrict__ bias,
            int* __restrict__ gidx, float* __restrict__ gvals) {
    __shared__ unsigned long long buf[2][1024];
    __shared__ float Ws[DD];
    const int b = blockIdx.x / NCLS;
    const int c = blockIdx.x % NCLS;
    const int t = threadIdx.x;

    if (t < DD) Ws[t] = W[t];
    __syncthreads();

    // per-thread f64 dot + exact f32 sigmoid for this thread's element
    float s = 0.0f;
    int row = -1;
    if (t < SS) row = c * SS + t;
    else if (c == 0 && t < SS + NQ) row = NSUP + (t - SS);   // query rows
    if (row >= 0) {
        const f4* x4 = (const f4*)(X + ((size_t)b * NN + row) * DD);
        double acc = 0.0;
        #pragma unroll
        for (int i = 0; i < DD / 4; ++i) {
            f4 xv = x4[i];
            acc += (double)xv.x * (double)Ws[4*i]
                 + (double)xv.y * (double)Ws[4*i+1]
                 + (double)xv.z * (double)Ws[4*i+2]
                 + (double)xv.w * (double)Ws[4*i+3];
        }
        float z32 = (float)acc;
        float u   = (z32 + bias[0]) / 100.0f;
        float e   = (float)exp(-(double)u);
        s = 1.0f / (1.0f + e);
    }

    if (c == 0 && t >= SS && t < SS + NQ) {       // emit queries directly
        int q = t - SS;
        gidx [b * MM + NCLS * KK + q] = NSUP + q;
        gvals[b * MM + NCLS * KK + q] = s;
    }

    unsigned long long v = 0ull;                  // pad sinks
    if (t < SS)
        v = ((unsigned long long)__float_as_uint(s) << 32) | (unsigned int)(1023 - t);

    int p = 0;
    for (int k = 2; k <= 1024; k <<= 1) {
        for (int j = k >> 1; j > 0; j >>= 1) {
            unsigned long long o;
            if (j >= 64) {
                buf[p][t] = v;
                __syncthreads();
                o = buf[p][t ^ j];
                p ^= 1;   // next reuse of this buffer is 2 stages (1 barrier) away
            } else {
                unsigned int lo = __shfl_xor((unsigned int)(v & 0xFFFFFFFFu), j);
                unsigned int hi = __shfl_xor((unsigned int)(v >> 32), j);
                o = ((unsigned long long)hi << 32) | lo;
            }
            bool keepMax = (((t & k) == 0) == ((t & j) == 0));
            v = keepMax ? (v > o ? v : o) : (v < o ? v : o);
        }
    }

    if (t < KK) {
        int li = 1023 - (int)(v & 0xFFFFFFFFull);
        gidx [b * MM + c * KK + t] = c * SS + li;
        gvals[b * MM + c * KK + t] = __uint_as_float((unsigned int)(v >> 32));
    }
}

// ---------------- fused new_A + new_X + idx: LDS-staged streaming row gather ----------------
__global__ void __launch_bounds__(256)
newxa_kernel(const float* __restrict__ A, const float* __restrict__ X,
             const int* __restrict__ gidx, const float* __restrict__ gvals,
             float* __restrict__ outA, float* __restrict__ outX, float* __restrict__ outIdx) {
    __shared__ int   cidx[MM];
    __shared__ float rowA[NN];
    const int bm = blockIdx.x;            // b*MM + i
    const int b  = bm / MM;
    const int* gb = gidx + b * MM;
    for (int j = threadIdx.x; j < MM; j += 256) cidx[j] = gb[j];
    __syncthreads();                      // cidx[bm - b*MM] needed below

    const int ri = cidx[bm - b * MM];

    // stream the full 16 KB A-row into LDS, coalesced, nontemporal (read-once data)
    const f4* arow4 = (const f4*)(A + ((size_t)b * NN + ri) * NN);
    f4* rowA4 = (f4*)rowA;
    #pragma unroll
    for (int j = 0; j < NN / 4 / 256; ++j) {
        int p = j * 256 + threadIdx.x;
        rowA4[p] = __builtin_nontemporal_load(arow4 + p);
    }

    if (threadIdx.x < DD) {
        float vscale = gvals[bm];
        float xv = X[((size_t)b * NN + ri) * DD + threadIdx.x] * vscale;
        __builtin_nontemporal_store(xv, outX + (size_t)bm * DD + threadIdx.x);
        if (threadIdx.x == 0) outIdx[bm] = (float)ri;
    }
    __syncthreads();

    // gather from LDS, write streaming float4 (MM = 4*524, rows 16B-aligned)
    float* orow = outA + (size_t)bm * MM;
    for (int jj = threadIdx.x * 4; jj < MM; jj += 1024) {
        f4 vv;
        vv.x = rowA[cidx[jj]];
        vv.y = rowA[cidx[jj + 1]];
        vv.z = rowA[cidx[jj + 2]];
        vv.w = rowA[cidx[jj + 3]];
        __builtin_nontemporal_store(vv, (f4*)(orow + jj));
    }
}

extern "C" void kernel_launch(void* const* d_in, const int* in_sizes, int n_in,
                              void* d_out, int out_size, void* d_ws, size_t ws_size,
                              hipStream_t stream) {
    const float* A  = (const float*)d_in[0];
    const float* X  = (const float*)d_in[1];
    const float* W  = (const float*)d_in[2];
    const float* bi = (const float*)d_in[3];

    float* outA   = (float*)d_out;                         // B*M*M
    float* outX   = outA + (size_t)BB * MM * MM;           // B*M*D
    float* outIdx = outX + (size_t)BB * MM * DD;           // B*M

    char* ws = (char*)d_ws;
    int*   gidx  = (int*)  ws;                 // B*M*4 = 33536
    float* gvals = (float*)(ws + 33536);       // B*M*4 = 33536

    topk_kernel<<<BB * NCLS, 1024, 0, stream>>>(X, W, bi, gidx, gvals);
    newxa_kernel<<<BB * MM, 256, 0, stream>>>(A, X, gidx, gvals, outA, outX, outIdx);
}